// Round 1
// baseline (336.935 us; speedup 1.0000x reference)
//
#include <hip/hip_runtime.h>

typedef _Float16 f16;
typedef __attribute__((ext_vector_type(4))) _Float16 f16x4;
typedef __attribute__((ext_vector_type(8))) _Float16 f16x8;
typedef __attribute__((ext_vector_type(4))) float f32x4;

#define MFMA16(a, b, c) __builtin_amdgcn_mfma_f32_16x16x32_f16((a), (b), (c), 0, 0, 0)

__device__ __forceinline__ f16x8 cvt8(float4 a, float4 b) {
    f16x8 r;
    r[0] = (f16)a.x; r[1] = (f16)a.y; r[2] = (f16)a.z; r[3] = (f16)a.w;
    r[4] = (f16)b.x; r[5] = (f16)b.y; r[6] = (f16)b.z; r[7] = (f16)b.w;
    return r;
}

// ---------------- pre-kernel: fp16 weights + fused bias constants into ws ----
__global__ void prep_kernel(const float* __restrict__ w_ih, const float* __restrict__ w_hh,
                            const float* __restrict__ b_ih, const float* __restrict__ b_hh,
                            const float* __restrict__ b_iah, const float* __restrict__ b_oah,
                            const float* __restrict__ W_in, const float* __restrict__ bias_in,
                            const float* __restrict__ W_out, const float* __restrict__ bias_out,
                            f16* __restrict__ Wc, f16* __restrict__ Whh, f16* __restrict__ Wih,
                            float* __restrict__ cstA, float* __restrict__ cstB,
                            float* __restrict__ biasc) {
    const int tid = threadIdx.x;
    for (int i = tid; i < 8192; i += 256)      // Wc[j][h]: j<64 -> W_in, else W_out
        Wc[i] = (f16)(i < 4096 ? W_in[i] : W_out[i - 4096]);
    for (int i = tid; i < 12288; i += 256) Whh[i] = (f16)w_hh[i];   // [192][64]
    for (int i = tid; i < 24576; i += 256) Wih[i] = (f16)w_ih[i];   // [192][128]
    for (int g = tid; g < 192; g += 256) {
        float s = b_ih[g];
        for (int i = 0; i < 64; ++i) s += w_ih[g * 128 + i] * b_iah[i];
        for (int i = 0; i < 64; ++i) s += w_ih[g * 128 + 64 + i] * b_oah[i];
        cstA[g] = s;          // goes inside i-gate side (pre-resetgate for n)
        cstB[g] = b_hh[g];    // goes on gh side (multiplied by resetgate for n)
    }
    for (int j = tid; j < 128; j += 256) biasc[j] = (j < 64) ? bias_in[j] : bias_out[j - 64];
}

// ---------------- fused main kernel: one workgroup per batch b ---------------
// Phase 1: hT[j][m] = f16(sum_h hidden[m,h]*Wc[j,h] + biasc[j])   (LDS, transposed)
// Phase 2: inputs[n][i] = sum_m Acat[n,m]*h_cat[m,i]  (A streamed from HBM, acc in regs)
// Phase 3: gi = inputs@w_ih^T, gh = hidden@w_hh^T, GRU gates, write out.
__global__ __launch_bounds__(512, 4) void gru_fused(
    const float* __restrict__ A, const float* __restrict__ hidden,
    const f16* __restrict__ Wc, const f16* __restrict__ Whh, const f16* __restrict__ Wih,
    const float* __restrict__ cstA, const float* __restrict__ cstB,
    const float* __restrict__ biasc, float* __restrict__ out) {
    __shared__ __align__(16) char lds_raw[59392];
    f16* hT  = (f16*)lds_raw;   // [128][232]  (k padded: [200,224) zeroed)
    f16* inp = (f16*)lds_raw;   // [208][136]  (reuses hT space after barrier)

    const int b = blockIdx.x;
    const float* Ab = A + (size_t)b * 80000;      // [400][200]
    const float* hb = hidden + (size_t)b * 12800; // [200][64]
    float* ob = out + (size_t)b * 12800;

    const int tid = threadIdx.x;
    const int w   = tid >> 6;
    const int l   = tid & 63;
    const int l15 = l & 15;
    const int lg  = l >> 4;

    // zero hT k-pad [200,224) so clamped A-reads at K-tail contribute 0
    for (int idx = tid; idx < 128 * 24; idx += 512) {
        int j = idx / 24, k = idx % 24;
        hT[j * 232 + 200 + k] = (f16)0.0f;
    }
    __syncthreads();

    // ---- Phase 1 ----
    for (int job = w; job < 104; job += 8) {   // 13 m-tiles x 8 j-tiles
        const int mt = job >> 3, jt = job & 7;
        const int m  = mt * 16 + l15;
        const int mc = m < 200 ? m : 199;      // clamp (values masked by store predicate)
        const int j  = jt * 16 + l15;
        f32x4 acc = {0.f, 0.f, 0.f, 0.f};
#pragma unroll
        for (int k0 = 0; k0 < 64; k0 += 32) {
            const int h = k0 + lg * 8;
            float4 r0 = *(const float4*)(hb + mc * 64 + h);
            float4 r1 = *(const float4*)(hb + mc * 64 + h + 4);
            f16x8 bf = *(const f16x8*)(Wc + j * 64 + h);
            acc = MFMA16(cvt8(r0, r1), bf, acc);
        }
        const float bc = biasc[j];
        const int m0 = mt * 16 + lg * 4;       // C/D row = lg*4 + reg
        if (m0 < 200) {
            f16x4 pk;
            pk[0] = (f16)(acc[0] + bc); pk[1] = (f16)(acc[1] + bc);
            pk[2] = (f16)(acc[2] + bc); pk[3] = (f16)(acc[3] + bc);
            *(f16x4*)(hT + j * 232 + m0) = pk;
        }
    }
    __syncthreads();

    // ---- Phase 2 ----
    const int hf = w >> 2;   // 0: A_in/h_in cols 0..63, 1: A_out/h_out cols 64..127
    const int wm = w & 3;
    f32x4 accC[4][4];
#pragma unroll
    for (int tt = 0; tt < 4; ++tt)
#pragma unroll
        for (int jt = 0; jt < 4; ++jt) accC[tt][jt] = (f32x4){0.f, 0.f, 0.f, 0.f};

#pragma unroll
    for (int tt = 0; tt < 4; ++tt) {
        const int t = wm + tt * 4;
        if (t < 13) {
            const int n  = t * 16 + l15;
            const int nc = n < 200 ? n : 199;  // clamp; rows >=200 never stored
            const float* arow = Ab + (size_t)(hf * 200 + nc) * 200;
            float4 p0 = *(const float4*)(arow + lg * 8);
            float4 p1 = *(const float4*)(arow + lg * 8 + 4);
#pragma unroll
            for (int k0 = 0; k0 < 224; k0 += 32) {   // k0 = 0..192
                f16x8 a = cvt8(p0, p1);
                if (k0 < 192) {                      // prefetch next K-step
                    int mn = k0 + 32 + lg * 8;
                    if (mn >= 200) mn = 192;         // clamp; hT[k>=200]=0 kills it
                    p0 = *(const float4*)(arow + mn);
                    p1 = *(const float4*)(arow + mn + 4);
                }
                const int kk = k0 + lg * 8;
#pragma unroll
                for (int jt = 0; jt < 4; ++jt) {
                    const int col = hf * 64 + jt * 16 + l15;
                    f16x8 bf = *(const f16x8*)(hT + col * 232 + kk);
                    accC[tt][jt] = MFMA16(a, bf, accC[tt][jt]);
                }
            }
        }
    }
    __syncthreads();   // all hT reads done before overwriting with inp

#pragma unroll
    for (int tt = 0; tt < 4; ++tt) {
        const int t = wm + tt * 4;
        if (t < 13) {
#pragma unroll
            for (int jt = 0; jt < 4; ++jt) {
                const int i = hf * 64 + jt * 16 + l15;
#pragma unroll
                for (int r = 0; r < 4; ++r) {
                    const int n = t * 16 + lg * 4 + r;
                    inp[n * 136 + i] = (f16)accC[tt][jt][r];
                }
            }
        }
    }
    __syncthreads();

    // ---- Phase 3 ----
    const int c   = w & 3;    // h-column tile (16 cols)
    const int wm2 = w >> 2;   // 0..1 -> M-tile parity
    const int hcol = c * 16 + l15;
    const float cAr = cstA[hcol], cAi = cstA[64 + hcol], cAn = cstA[128 + hcol];
    const float cBr = cstB[hcol], cBi = cstB[64 + hcol], cBn = cstB[128 + hcol];

    for (int t = wm2; t < 13; t += 2) {
        const int n  = t * 16 + l15;
        const int nc = n < 200 ? n : 199;
        f32x4 gir = {0.f,0.f,0.f,0.f}, gii = {0.f,0.f,0.f,0.f}, gin = {0.f,0.f,0.f,0.f};
        f32x4 ghr = {0.f,0.f,0.f,0.f}, ghi = {0.f,0.f,0.f,0.f}, ghn = {0.f,0.f,0.f,0.f};
#pragma unroll
        for (int k0 = 0; k0 < 128; k0 += 32) {   // gi: K = 128
            const int kk = k0 + lg * 8;
            f16x8 a = *(const f16x8*)(inp + n * 136 + kk);
            gir = MFMA16(a, *(const f16x8*)(Wih + (hcol      ) * 128 + kk), gir);
            gii = MFMA16(a, *(const f16x8*)(Wih + (64  + hcol) * 128 + kk), gii);
            gin = MFMA16(a, *(const f16x8*)(Wih + (128 + hcol) * 128 + kk), gin);
        }
#pragma unroll
        for (int k0 = 0; k0 < 64; k0 += 32) {    // gh: K = 64
            const int h = k0 + lg * 8;
            float4 r0 = *(const float4*)(hb + nc * 64 + h);
            float4 r1 = *(const float4*)(hb + nc * 64 + h + 4);
            f16x8 a = cvt8(r0, r1);
            ghr = MFMA16(a, *(const f16x8*)(Whh + (hcol      ) * 64 + h), ghr);
            ghi = MFMA16(a, *(const f16x8*)(Whh + (64  + hcol) * 64 + h), ghi);
            ghn = MFMA16(a, *(const f16x8*)(Whh + (128 + hcol) * 64 + h), ghn);
        }
#pragma unroll
        for (int r = 0; r < 4; ++r) {
            const int row = t * 16 + lg * 4 + r;
            if (row < 200) {
                const float hv = hb[row * 64 + hcol];
                const float xr = gir[r] + ghr[r] + cAr + cBr;
                const float xi = gii[r] + ghi[r] + cAi + cBi;
                const float rg = 1.0f / (1.0f + __expf(-xr));
                const float ig = 1.0f / (1.0f + __expf(-xi));
                const float xn = gin[r] + cAn + rg * (ghn[r] + cBn);
                const float e2 = __expf(2.0f * xn);
                const float ng = 1.0f - 2.0f / (e2 + 1.0f);
                ob[row * 64 + hcol] = hv + ig * (ng - hv);
            }
        }
    }
}

extern "C" void kernel_launch(void* const* d_in, const int* in_sizes, int n_in,
                              void* d_out, int out_size, void* d_ws, size_t ws_size,
                              hipStream_t stream) {
    const float* A        = (const float*)d_in[0];
    const float* hidden   = (const float*)d_in[1];
    const float* w_ih     = (const float*)d_in[2];
    const float* w_hh     = (const float*)d_in[3];
    const float* b_ih     = (const float*)d_in[4];
    const float* b_hh     = (const float*)d_in[5];
    const float* b_iah    = (const float*)d_in[6];
    const float* b_oah    = (const float*)d_in[7];
    const float* W_in     = (const float*)d_in[8];
    const float* bias_in  = (const float*)d_in[9];
    const float* W_out    = (const float*)d_in[10];
    const float* bias_out = (const float*)d_in[11];
    float* out = (float*)d_out;

    char* wsb = (char*)d_ws;
    f16* Wc      = (f16*)wsb;            // 8192 f16
    f16* Whh     = Wc + 8192;            // 12288 f16
    f16* Wih     = Whh + 12288;          // 24576 f16
    float* cstA  = (float*)(wsb + 90112);
    float* cstB  = cstA + 192;
    float* biasc = cstB + 192;           // total 92160 bytes of ws

    prep_kernel<<<dim3(1), dim3(256), 0, stream>>>(
        w_ih, w_hh, b_ih, b_hh, b_iah, b_oah, W_in, bias_in, W_out, bias_out,
        Wc, Whh, Wih, cstA, cstB, biasc);
    gru_fused<<<dim3(1024), dim3(512), 0, stream>>>(
        A, hidden, Wc, Whh, Wih, cstA, cstB, biasc, out);
}

// Round 2
// 250.922 us; speedup vs baseline: 1.3428x; 1.3428x over previous
//
#include <hip/hip_runtime.h>

typedef _Float16 f16;
typedef __attribute__((ext_vector_type(4))) _Float16 f16x4;
typedef __attribute__((ext_vector_type(8))) _Float16 f16x8;
typedef __attribute__((ext_vector_type(4))) float f32x4;

#define MFMA16(a, b, c) __builtin_amdgcn_mfma_f32_16x16x32_f16((a), (b), (c), 0, 0, 0)

__device__ __forceinline__ f16x8 cvt8(float4 a, float4 b) {
    f16x8 r;
    r[0] = (f16)a.x; r[1] = (f16)a.y; r[2] = (f16)a.z; r[3] = (f16)a.w;
    r[4] = (f16)b.x; r[5] = (f16)b.y; r[6] = (f16)b.z; r[7] = (f16)b.w;
    return r;
}

// ---------------- pre-kernel: fp16 weights + fused bias constants into ws ----
// grid-strided over 64 blocks x 256 threads so it is noise in the timeline.
__global__ void prep_kernel(const float* __restrict__ w_ih, const float* __restrict__ w_hh,
                            const float* __restrict__ b_ih, const float* __restrict__ b_hh,
                            const float* __restrict__ b_iah, const float* __restrict__ b_oah,
                            const float* __restrict__ W_in, const float* __restrict__ bias_in,
                            const float* __restrict__ W_out, const float* __restrict__ bias_out,
                            f16* __restrict__ Wc, f16* __restrict__ Whh, f16* __restrict__ Wih,
                            float* __restrict__ cstA, float* __restrict__ cstB,
                            float* __restrict__ biasc) {
    const int gid = blockIdx.x * 256 + threadIdx.x;
    const int gstride = gridDim.x * 256;
    for (int i = gid; i < 8192; i += gstride)      // Wc[j][h]: j<64 -> W_in, else W_out
        Wc[i] = (f16)(i < 4096 ? W_in[i] : W_out[i - 4096]);
    for (int i = gid; i < 12288; i += gstride) Whh[i] = (f16)w_hh[i];   // [192][64]
    for (int i = gid; i < 24576; i += gstride) Wih[i] = (f16)w_ih[i];   // [192][128]
    // cstA: 192 rows x 128-lane partial dot -> do (g, quarter) jobs: 768 jobs of 32 MACs
    for (int job = gid; job < 768; job += gstride) {
        const int g = job >> 2, q = job & 3;
        float s = (q == 0) ? b_ih[g] : 0.0f;
        const float* wr = w_ih + g * 128 + q * 32;
        for (int i = 0; i < 32; ++i)
            s += wr[i] * ((q * 32 + i < 64) ? b_iah[q * 32 + i] : b_oah[q * 32 + i - 64]);
        atomicAdd(&cstA[g], s);   // cstA zeroed by zero_kernel below
    }
    for (int g = gid; g < 192; g += gstride) cstB[g] = b_hh[g];
    for (int j = gid; j < 128; j += gstride) biasc[j] = (j < 64) ? bias_in[j] : bias_out[j - 64];
}

__global__ void zero_kernel(float* __restrict__ cstA) {
    if (threadIdx.x < 192) cstA[threadIdx.x] = 0.0f;
}

// ---------------- fused main kernel: one workgroup per batch b ---------------
// Phase 1: hT[j][m] = f16(sum_h hidden[m,h]*Wc[j,h] + biasc[j])   (LDS, transposed)
// Phase 2: inputs[n][i] = sum_m Acat[n,m]*h_cat[m,i]  (A streamed from HBM, acc in regs)
// Phase 3: gi = inputs@w_ih^T, gh = hidden@w_hh^T, GRU gates, write out.
// __launch_bounds__(512, 2): LDS (59.4 KB) caps us at 2 WGs/CU anyway, so ask
// for 2 waves/EU (= 16 waves/CU = 2 WGs/CU) -> 128-VGPR budget -> no spill.
__global__ __launch_bounds__(512, 2) void gru_fused(
    const float* __restrict__ A, const float* __restrict__ hidden,
    const f16* __restrict__ Wc, const f16* __restrict__ Whh, const f16* __restrict__ Wih,
    const float* __restrict__ cstA, const float* __restrict__ cstB,
    const float* __restrict__ biasc, float* __restrict__ out) {
    __shared__ __align__(16) char lds_raw[59392];
    f16* hT  = (f16*)lds_raw;   // [128][232]  (k padded: [200,224) zeroed)
    f16* inp = (f16*)lds_raw;   // [208][136]  (reuses hT space after barrier)

    const int b = blockIdx.x;
    const float* Ab = A + (size_t)b * 80000;      // [400][200]
    const float* hb = hidden + (size_t)b * 12800; // [200][64]
    float* ob = out + (size_t)b * 12800;

    const int tid = threadIdx.x;
    const int w   = tid >> 6;
    const int l   = tid & 63;
    const int l15 = l & 15;
    const int lg  = l >> 4;

    // zero hT k-pad [200,224) so clamped A-reads at K-tail contribute 0
    for (int idx = tid; idx < 128 * 24; idx += 512) {
        int j = idx / 24, k = idx % 24;
        hT[j * 232 + 200 + k] = (f16)0.0f;
    }
    __syncthreads();

    // ---- Phase 1 ----
    for (int job = w; job < 104; job += 8) {   // 13 m-tiles x 8 j-tiles
        const int mt = job >> 3, jt = job & 7;
        const int m  = mt * 16 + l15;
        const int mc = m < 200 ? m : 199;      // clamp (values masked by store predicate)
        const int j  = jt * 16 + l15;
        f32x4 acc = {0.f, 0.f, 0.f, 0.f};
#pragma unroll
        for (int k0 = 0; k0 < 64; k0 += 32) {
            const int h = k0 + lg * 8;
            float4 r0 = *(const float4*)(hb + mc * 64 + h);
            float4 r1 = *(const float4*)(hb + mc * 64 + h + 4);
            f16x8 bf = *(const f16x8*)(Wc + j * 64 + h);
            acc = MFMA16(cvt8(r0, r1), bf, acc);
        }
        const float bc = biasc[j];
        const int m0 = mt * 16 + lg * 4;       // C/D row = lg*4 + reg
        if (m0 < 200) {
            f16x4 pk;
            pk[0] = (f16)(acc[0] + bc); pk[1] = (f16)(acc[1] + bc);
            pk[2] = (f16)(acc[2] + bc); pk[3] = (f16)(acc[3] + bc);
            *(f16x4*)(hT + j * 232 + m0) = pk;
        }
    }
    __syncthreads();

    // ---- Phase 2 ----
    const int hf = w >> 2;   // 0: A_in/h_in cols 0..63, 1: A_out/h_out cols 64..127
    const int wm = w & 3;
    f32x4 accC[4][4];
#pragma unroll
    for (int tt = 0; tt < 4; ++tt)
#pragma unroll
        for (int jt = 0; jt < 4; ++jt) accC[tt][jt] = (f32x4){0.f, 0.f, 0.f, 0.f};

#pragma unroll
    for (int tt = 0; tt < 4; ++tt) {
        const int t = wm + tt * 4;
        if (t < 13) {
            const int n  = t * 16 + l15;
            const int nc = n < 200 ? n : 199;  // clamp; rows >=200 never stored
            const float* arow = Ab + (size_t)(hf * 200 + nc) * 200;
            float4 p0 = *(const float4*)(arow + lg * 8);
            float4 p1 = *(const float4*)(arow + lg * 8 + 4);
#pragma unroll
            for (int k0 = 0; k0 < 224; k0 += 32) {   // k0 = 0..192
                f16x8 a = cvt8(p0, p1);
                if (k0 < 192) {                      // prefetch next K-step
                    int mn = k0 + 32 + lg * 8;
                    if (mn >= 200) mn = 192;         // clamp; hT[k>=200]=0 kills it
                    p0 = *(const float4*)(arow + mn);
                    p1 = *(const float4*)(arow + mn + 4);
                }
                const int kk = k0 + lg * 8;
#pragma unroll
                for (int jt = 0; jt < 4; ++jt) {
                    const int col = hf * 64 + jt * 16 + l15;
                    f16x8 bf = *(const f16x8*)(hT + col * 232 + kk);
                    accC[tt][jt] = MFMA16(a, bf, accC[tt][jt]);
                }
            }
        }
    }
    __syncthreads();   // all hT reads done before overwriting with inp

#pragma unroll
    for (int tt = 0; tt < 4; ++tt) {
        const int t = wm + tt * 4;
        if (t < 13) {
#pragma unroll
            for (int jt = 0; jt < 4; ++jt) {
                const int i = hf * 64 + jt * 16 + l15;
#pragma unroll
                for (int r = 0; r < 4; ++r) {
                    const int n = t * 16 + lg * 4 + r;
                    inp[n * 136 + i] = (f16)accC[tt][jt][r];
                }
            }
        }
    }
    __syncthreads();

    // ---- Phase 3 ----
    const int c   = w & 3;    // h-column tile (16 cols)
    const int wm2 = w >> 2;   // 0..1 -> M-tile parity
    const int hcol = c * 16 + l15;
    const float cAr = cstA[hcol], cAi = cstA[64 + hcol], cAn = cstA[128 + hcol];
    const float cBr = cstB[hcol], cBi = cstB[64 + hcol], cBn = cstB[128 + hcol];

    for (int t = wm2; t < 13; t += 2) {
        const int n  = t * 16 + l15;
        const int nc = n < 200 ? n : 199;
        f32x4 gir = {0.f,0.f,0.f,0.f}, gii = {0.f,0.f,0.f,0.f}, gin = {0.f,0.f,0.f,0.f};
        f32x4 ghr = {0.f,0.f,0.f,0.f}, ghi = {0.f,0.f,0.f,0.f}, ghn = {0.f,0.f,0.f,0.f};
#pragma unroll
        for (int k0 = 0; k0 < 128; k0 += 32) {   // gi: K = 128
            const int kk = k0 + lg * 8;
            f16x8 a = *(const f16x8*)(inp + n * 136 + kk);
            gir = MFMA16(a, *(const f16x8*)(Wih + (hcol      ) * 128 + kk), gir);
            gii = MFMA16(a, *(const f16x8*)(Wih + (64  + hcol) * 128 + kk), gii);
            gin = MFMA16(a, *(const f16x8*)(Wih + (128 + hcol) * 128 + kk), gin);
        }
#pragma unroll
        for (int k0 = 0; k0 < 64; k0 += 32) {    // gh: K = 64
            const int h = k0 + lg * 8;
            float4 r0 = *(const float4*)(hb + nc * 64 + h);
            float4 r1 = *(const float4*)(hb + nc * 64 + h + 4);
            f16x8 a = cvt8(r0, r1);
            ghr = MFMA16(a, *(const f16x8*)(Whh + (hcol      ) * 64 + h), ghr);
            ghi = MFMA16(a, *(const f16x8*)(Whh + (64  + hcol) * 64 + h), ghi);
            ghn = MFMA16(a, *(const f16x8*)(Whh + (128 + hcol) * 64 + h), ghn);
        }
#pragma unroll
        for (int r = 0; r < 4; ++r) {
            const int row = t * 16 + lg * 4 + r;
            if (row < 200) {
                const float hv = hb[row * 64 + hcol];
                const float xr = gir[r] + ghr[r] + cAr + cBr;
                const float xi = gii[r] + ghi[r] + cAi + cBi;
                const float rg = 1.0f / (1.0f + __expf(-xr));
                const float ig = 1.0f / (1.0f + __expf(-xi));
                const float xn = gin[r] + cAn + rg * (ghn[r] + cBn);
                const float e2 = __expf(2.0f * xn);
                const float ng = 1.0f - 2.0f / (e2 + 1.0f);
                ob[row * 64 + hcol] = hv + ig * (ng - hv);
            }
        }
    }
}

extern "C" void kernel_launch(void* const* d_in, const int* in_sizes, int n_in,
                              void* d_out, int out_size, void* d_ws, size_t ws_size,
                              hipStream_t stream) {
    const float* A        = (const float*)d_in[0];
    const float* hidden   = (const float*)d_in[1];
    const float* w_ih     = (const float*)d_in[2];
    const float* w_hh     = (const float*)d_in[3];
    const float* b_ih     = (const float*)d_in[4];
    const float* b_hh     = (const float*)d_in[5];
    const float* b_iah    = (const float*)d_in[6];
    const float* b_oah    = (const float*)d_in[7];
    const float* W_in     = (const float*)d_in[8];
    const float* bias_in  = (const float*)d_in[9];
    const float* W_out    = (const float*)d_in[10];
    const float* bias_out = (const float*)d_in[11];
    float* out = (float*)d_out;

    char* wsb = (char*)d_ws;
    f16* Wc      = (f16*)wsb;            // 8192 f16
    f16* Whh     = Wc + 8192;            // 12288 f16
    f16* Wih     = Whh + 12288;          // 24576 f16
    float* cstA  = (float*)(wsb + 90112);
    float* cstB  = cstA + 192;
    float* biasc = cstB + 192;           // total 92160 bytes of ws

    zero_kernel<<<dim3(1), dim3(256), 0, stream>>>(cstA);
    prep_kernel<<<dim3(64), dim3(256), 0, stream>>>(
        w_ih, w_hh, b_ih, b_hh, b_iah, b_oah, W_in, bias_in, W_out, bias_out,
        Wc, Whh, Wih, cstA, cstB, biasc);
    gru_fused<<<dim3(1024), dim3(512), 0, stream>>>(
        A, hidden, Wc, Whh, Wih, cstA, cstB, biasc, out);
}

// Round 3
// 155.362 us; speedup vs baseline: 2.1687x; 1.6151x over previous
//
#include <hip/hip_runtime.h>

typedef _Float16 f16;
typedef __attribute__((ext_vector_type(4))) _Float16 f16x4;
typedef __attribute__((ext_vector_type(8))) _Float16 f16x8;
typedef __attribute__((ext_vector_type(4))) float f32x4;

#define MFMA16(a, b, c) __builtin_amdgcn_mfma_f32_16x16x32_f16((a), (b), (c), 0, 0, 0)

__device__ __forceinline__ f16x8 cvt8(float4 a, float4 b) {
    f16x8 r;
    r[0] = (f16)a.x; r[1] = (f16)a.y; r[2] = (f16)a.z; r[3] = (f16)a.w;
    r[4] = (f16)b.x; r[5] = (f16)b.y; r[6] = (f16)b.z; r[7] = (f16)b.w;
    return r;
}

// ---------------- pre-kernel: fp16 weights + fused bias constants into ws ----
__global__ void prep_kernel(const float* __restrict__ w_ih, const float* __restrict__ w_hh,
                            const float* __restrict__ b_ih, const float* __restrict__ b_hh,
                            const float* __restrict__ b_iah, const float* __restrict__ b_oah,
                            const float* __restrict__ W_in, const float* __restrict__ bias_in,
                            const float* __restrict__ W_out, const float* __restrict__ bias_out,
                            f16* __restrict__ Wc, f16* __restrict__ Whh, f16* __restrict__ Wih,
                            float* __restrict__ cstA, float* __restrict__ cstB,
                            float* __restrict__ biasc) {
    const int gid = blockIdx.x * 256 + threadIdx.x;
    const int gstride = gridDim.x * 256;
    for (int i = gid; i < 8192; i += gstride)      // Wc[j][h]: j<64 -> W_in, else W_out
        Wc[i] = (f16)(i < 4096 ? W_in[i] : W_out[i - 4096]);
    for (int i = gid; i < 12288; i += gstride) Whh[i] = (f16)w_hh[i];   // [192][64]
    for (int i = gid; i < 24576; i += gstride) Wih[i] = (f16)w_ih[i];   // [192][128]
    for (int job = gid; job < 768; job += gstride) {
        const int g = job >> 2, q = job & 3;
        float s = (q == 0) ? b_ih[g] : 0.0f;
        const float* wr = w_ih + g * 128 + q * 32;
        for (int i = 0; i < 32; ++i)
            s += wr[i] * ((q * 32 + i < 64) ? b_iah[q * 32 + i] : b_oah[q * 32 + i - 64]);
        atomicAdd(&cstA[g], s);
    }
    for (int g = gid; g < 192; g += gstride) cstB[g] = b_hh[g];
    for (int j = gid; j < 128; j += gstride) biasc[j] = (j < 64) ? bias_in[j] : bias_out[j - 64];
}

__global__ void zero_kernel(float* __restrict__ cstA) {
    if (threadIdx.x < 192) cstA[threadIdx.x] = 0.0f;
}

// ---------------- fused main kernel: one workgroup (512 thr) per batch b -----
// LDS (64000 B static):
//   phase 1-2:  hT [128 cols][200 k] f16 @0        (51200 B)  h_cat^T
//               hA [2][16][200]      f16 @51200    (12800 B)  staged A M-tile
//   phase 3:    inp [208][136]       f16 @0        (56576 B)
__global__ __launch_bounds__(512, 2) void gru_fused(
    const float* __restrict__ A, const float* __restrict__ hidden,
    const f16* __restrict__ Wc, const f16* __restrict__ Whh, const f16* __restrict__ Wih,
    const float* __restrict__ cstA, const float* __restrict__ cstB,
    const float* __restrict__ biasc, float* __restrict__ out) {
    __shared__ __align__(16) char lds_raw[64000];
    f16* hT  = (f16*)lds_raw;             // [128][200]
    f16* hA  = (f16*)(lds_raw + 51200);   // [2][16][200]
    f16* inp = (f16*)lds_raw;             // [208][136]

    const int b = blockIdx.x;
    const float* Ab = A + (size_t)b * 80000;      // [400][200]
    const float* hb = hidden + (size_t)b * 12800; // [200][64]
    float* ob = out + (size_t)b * 12800;

    const int tid = threadIdx.x;
    const int w   = tid >> 6;
    const int l   = tid & 63;
    const int l15 = l & 15;
    const int lg  = l >> 4;

    // ---- Phase 1: hT[j][m] = f16(hidden[m,:]@Wc[j,:] + biasc[j]) ----
    // each wave owns m-tiles {w, w+8}; hidden tile loaded ONCE per mt.
    for (int mt = w; mt < 13; mt += 8) {
        const int m  = mt * 16 + l15;
        const int mc = m < 200 ? m : 199;
        const float* hrow = hb + mc * 64;
        float4 r0 = *(const float4*)(hrow + lg * 8);
        float4 r1 = *(const float4*)(hrow + lg * 8 + 4);
        float4 r2 = *(const float4*)(hrow + 32 + lg * 8);
        float4 r3 = *(const float4*)(hrow + 32 + lg * 8 + 4);
        f16x8 a0 = cvt8(r0, r1), a1 = cvt8(r2, r3);
        const int m0 = mt * 16 + lg * 4;
#pragma unroll
        for (int jt = 0; jt < 8; ++jt) {
            const int j = jt * 16 + l15;
            f32x4 acc = {0.f, 0.f, 0.f, 0.f};
            acc = MFMA16(a0, *(const f16x8*)(Wc + j * 64 + lg * 8), acc);
            acc = MFMA16(a1, *(const f16x8*)(Wc + j * 64 + 32 + lg * 8), acc);
            const float bc = biasc[j];
            if (m0 < 200) {
                f16x4 pk;
                pk[0] = (f16)(acc[0] + bc); pk[1] = (f16)(acc[1] + bc);
                pk[2] = (f16)(acc[2] + bc); pk[3] = (f16)(acc[3] + bc);
                *(f16x4*)(hT + j * 200 + m0) = pk;
            }
        }
    }
    __syncthreads();

    // ---- Phase 2: inputs = A_cat @ h_cat, A staged coalesced via LDS ----
    // wave w -> output col-tile [w*16, w*16+16), A-half = w>>2.
    const int half = w >> 2;
    const f16* hAp = hA + half * 3200 + l15 * 200;
    const f16* hTp = hT + (w * 16 + l15) * 200;

    // per-thread staging map: 1600 float4-units (2 halves x 16 rows x 50 units)
    int s_h[4], s_row[4], s_unit[4]; bool s_act[4];
#pragma unroll
    for (int r = 0; r < 4; ++r) {
        const int idx = tid + r * 512;
        s_act[r] = idx < 1600;
        const int ic = s_act[r] ? idx : 0;
        s_h[r] = ic / 800;
        const int rem = ic % 800;
        s_row[r] = rem / 50; s_unit[r] = rem % 50;
    }

    f32x4 accC[13];
#pragma unroll
    for (int t = 0; t < 13; ++t) accC[t] = (f32x4){0.f, 0.f, 0.f, 0.f};

    // stage tile 0
    {
        float4 v[4];
#pragma unroll
        for (int r = 0; r < 4; ++r) if (s_act[r]) {
            const int n = s_row[r];           // tile 0
            const int nc = n < 200 ? n : 199;
            v[r] = *(const float4*)(Ab + (size_t)(s_h[r] * 200 + nc) * 200 + s_unit[r] * 4);
        }
#pragma unroll
        for (int r = 0; r < 4; ++r) if (s_act[r]) {
            const int idx = tid + r * 512;
            f16x4 pk;
            pk[0] = (f16)v[r].x; pk[1] = (f16)v[r].y;
            pk[2] = (f16)v[r].z; pk[3] = (f16)v[r].w;
            *(f16x4*)(hA + idx * 4) = pk;
        }
    }
    __syncthreads();

#pragma unroll
    for (int t = 0; t < 13; ++t) {
        float4 v[4];
        if (t < 12) {                          // issue next tile's loads early (T14)
#pragma unroll
            for (int r = 0; r < 4; ++r) if (s_act[r]) {
                const int n = (t + 1) * 16 + s_row[r];
                const int nc = n < 200 ? n : 199;
                v[r] = *(const float4*)(Ab + (size_t)(s_h[r] * 200 + nc) * 200 + s_unit[r] * 4);
            }
        }
        // compute tile t: 7 K-steps, 1 MFMA each
#pragma unroll
        for (int k0 = 0; k0 < 224; k0 += 32) {
            f16x8 a;
            if (k0 == 192) {
                if (lg == 0) a = *(const f16x8*)(hAp + 192);
                else {
                    f16x8 z;
#pragma unroll
                    for (int q = 0; q < 8; ++q) z[q] = (f16)0.0f;
                    a = z;
                }
            } else {
                a = *(const f16x8*)(hAp + k0 + lg * 8);
            }
            f16x8 bf = *(const f16x8*)(hTp + k0 + lg * 8);
            accC[t] = MFMA16(a, bf, accC[t]);
        }
        __syncthreads();                       // all reads of hA done
        if (t < 12) {
#pragma unroll
            for (int r = 0; r < 4; ++r) if (s_act[r]) {
                const int idx = tid + r * 512;
                f16x4 pk;
                pk[0] = (f16)v[r].x; pk[1] = (f16)v[r].y;
                pk[2] = (f16)v[r].z; pk[3] = (f16)v[r].w;
                *(f16x4*)(hA + idx * 4) = pk;
            }
        }
        __syncthreads();                       // writes visible
    }

    // spill accC -> inp (hT/hA dead now)
#pragma unroll
    for (int t = 0; t < 13; ++t) {
#pragma unroll
        for (int r = 0; r < 4; ++r) {
            const int n = t * 16 + lg * 4 + r;
            inp[n * 136 + w * 16 + l15] = (f16)accC[t][r];
        }
    }
    __syncthreads();

    // ---- Phase 3: gi = inputs@w_ih^T, gh = hidden@w_hh^T, gates, store ----
    const int c   = w & 3;
    const int wm2 = w >> 2;
    const int hcol = c * 16 + l15;
    // hoist loop-invariant weight fragments into registers
    f16x8 Wf0[4], Wf1[4], Wf2[4];
#pragma unroll
    for (int k = 0; k < 4; ++k) {
        Wf0[k] = *(const f16x8*)(Wih + (hcol      ) * 128 + k * 32 + lg * 8);
        Wf1[k] = *(const f16x8*)(Wih + (64  + hcol) * 128 + k * 32 + lg * 8);
        Wf2[k] = *(const f16x8*)(Wih + (128 + hcol) * 128 + k * 32 + lg * 8);
    }
    f16x8 Hf0[2], Hf1[2], Hf2[2];
#pragma unroll
    for (int k = 0; k < 2; ++k) {
        Hf0[k] = *(const f16x8*)(Whh + (hcol      ) * 64 + k * 32 + lg * 8);
        Hf1[k] = *(const f16x8*)(Whh + (64  + hcol) * 64 + k * 32 + lg * 8);
        Hf2[k] = *(const f16x8*)(Whh + (128 + hcol) * 64 + k * 32 + lg * 8);
    }
    const float cAr = cstA[hcol], cAi = cstA[64 + hcol], cAn = cstA[128 + hcol];
    const float cBr = cstB[hcol], cBi = cstB[64 + hcol], cBn = cstB[128 + hcol];

    for (int t = wm2; t < 13; t += 2) {
        const int n  = t * 16 + l15;
        const int nc = n < 200 ? n : 199;
        f32x4 gir = {0.f,0.f,0.f,0.f}, gii = {0.f,0.f,0.f,0.f}, gin = {0.f,0.f,0.f,0.f};
        f32x4 ghr = {0.f,0.f,0.f,0.f}, ghi = {0.f,0.f,0.f,0.f}, ghn = {0.f,0.f,0.f,0.f};
#pragma unroll
        for (int k = 0; k < 4; ++k) {          // gi: K = 128
            f16x8 a = *(const f16x8*)(inp + n * 136 + k * 32 + lg * 8);
            gir = MFMA16(a, Wf0[k], gir);
            gii = MFMA16(a, Wf1[k], gii);
            gin = MFMA16(a, Wf2[k], gin);
        }
#pragma unroll
        for (int k = 0; k < 2; ++k) {          // gh: K = 64
            const int h = k * 32 + lg * 8;
            float4 r0 = *(const float4*)(hb + nc * 64 + h);
            float4 r1 = *(const float4*)(hb + nc * 64 + h + 4);
            f16x8 a = cvt8(r0, r1);
            ghr = MFMA16(a, Hf0[k], ghr);
            ghi = MFMA16(a, Hf1[k], ghi);
            ghn = MFMA16(a, Hf2[k], ghn);
        }
#pragma unroll
        for (int r = 0; r < 4; ++r) {
            const int row = t * 16 + lg * 4 + r;
            if (row < 200) {
                const float hv = hb[row * 64 + hcol];
                const float xr = gir[r] + ghr[r] + cAr + cBr;
                const float xi = gii[r] + ghi[r] + cAi + cBi;
                const float rg = 1.0f / (1.0f + __expf(-xr));
                const float ig = 1.0f / (1.0f + __expf(-xi));
                const float xn = gin[r] + cAn + rg * (ghn[r] + cBn);
                const float e2 = __expf(2.0f * xn);
                const float ng = 1.0f - 2.0f / (e2 + 1.0f);
                ob[row * 64 + hcol] = hv + ig * (ng - hv);
            }
        }
    }
}

extern "C" void kernel_launch(void* const* d_in, const int* in_sizes, int n_in,
                              void* d_out, int out_size, void* d_ws, size_t ws_size,
                              hipStream_t stream) {
    const float* A        = (const float*)d_in[0];
    const float* hidden   = (const float*)d_in[1];
    const float* w_ih     = (const float*)d_in[2];
    const float* w_hh     = (const float*)d_in[3];
    const float* b_ih     = (const float*)d_in[4];
    const float* b_hh     = (const float*)d_in[5];
    const float* b_iah    = (const float*)d_in[6];
    const float* b_oah    = (const float*)d_in[7];
    const float* W_in     = (const float*)d_in[8];
    const float* bias_in  = (const float*)d_in[9];
    const float* W_out    = (const float*)d_in[10];
    const float* bias_out = (const float*)d_in[11];
    float* out = (float*)d_out;

    char* wsb = (char*)d_ws;
    f16* Wc      = (f16*)wsb;            // 8192 f16
    f16* Whh     = Wc + 8192;            // 12288 f16
    f16* Wih     = Whh + 12288;          // 24576 f16
    float* cstA  = (float*)(wsb + 90112);
    float* cstB  = cstA + 192;
    float* biasc = cstB + 192;           // total 92160 bytes of ws

    zero_kernel<<<dim3(1), dim3(256), 0, stream>>>(cstA);
    prep_kernel<<<dim3(64), dim3(256), 0, stream>>>(
        w_ih, w_hh, b_ih, b_hh, b_iah, b_oah, W_in, bias_in, W_out, bias_out,
        Wc, Whh, Wih, cstA, cstB, biasc);
    gru_fused<<<dim3(1024), dim3(512), 0, stream>>>(
        A, hidden, Wc, Whh, Wih, cstA, cstB, biasc, out);
}